// Round 3
// baseline (223.110 us; speedup 1.0000x reference)
//
#include <hip/hip_runtime.h>

#define IN_DIM 256
#define U_DIM  512
#define L2E    1.44269504088896340736f

// ---------- prefuse params into float4 (sigma*l2e, mu*sigma*l2e, W*erev, W) ----------
__global__ void k_fuse(const float* __restrict__ mu, const float* __restrict__ sigma,
                       const float* __restrict__ W, const float* __restrict__ erev,
                       const float* __restrict__ smu, const float* __restrict__ ssig,
                       const float* __restrict__ sW, const float* __restrict__ serev,
                       float4* __restrict__ pf4, float4* __restrict__ sf4) {
    int i = blockIdx.x * blockDim.x + threadIdx.x;
    const int UU = U_DIM * U_DIM;
    const int SU = IN_DIM * U_DIM;
    if (i < UU) {
        float s = sigma[i] * L2E;
        float w = W[i];
        pf4[i] = make_float4(s, mu[i] * s, w * erev[i], w);
    } else if (i < UU + SU) {
        int j = i - UU;
        float s = ssig[j] * L2E;
        float w = sW[j];
        sf4[j] = make_float4(s, smu[j] * s, w * serev[j], w);
    }
}

// ---------- sensory sums: tile 4 rows x 64 u; 512 thr = 64 lanes x 8 strips (32 i each) ----------
__global__ __launch_bounds__(512, 8) void k_sensory(
    const float* __restrict__ inputs, const float* __restrict__ input_w,
    const float* __restrict__ input_b, const float4* __restrict__ sf4,
    float* __restrict__ wnum_s, float* __restrict__ wden_s) {
    __shared__ __align__(16) float xs[4 * IN_DIM];   // 4 KB
    __shared__ float red[8 * 4 * 64 * 2];            // 16 KB
    const int tid = threadIdx.x;
    const int b0 = blockIdx.x * 4;
    const int u0 = blockIdx.y * 64;

    #pragma unroll
    for (int k = 0; k < 2; ++k) {
        int idx = tid + k * 512;
        int r = idx >> 8, i = idx & 255;
        xs[idx] = fmaf(inputs[(b0 + r) * IN_DIM + i], input_w[i], input_b[i]);
    }
    __syncthreads();

    const int ul = tid & 63;
    const int strip = tid >> 6;
    const int u = u0 + ul;
    float nacc[4], dacc[4];
    #pragma unroll
    for (int r = 0; r < 4; ++r) { nacc[r] = 0.f; dacc[r] = 0.f; }

    const int i0 = strip * 32;
    for (int ic = 0; ic < 32; ic += 4) {
        const int i = i0 + ic;
        float4 q0 = sf4[(i + 0) * U_DIM + u];
        float4 q1 = sf4[(i + 1) * U_DIM + u];
        float4 q2 = sf4[(i + 2) * U_DIM + u];
        float4 q3 = sf4[(i + 3) * U_DIM + u];
        #pragma unroll
        for (int r = 0; r < 4; ++r) {
            const float4 x4 = *reinterpret_cast<const float4*>(&xs[r * IN_DIM + i]);
            {
                float e = __builtin_amdgcn_exp2f(fmaf(-q0.x, x4.x, q0.y));
                float p = __builtin_amdgcn_rcpf(1.f + e);
                nacc[r] = fmaf(q0.z, p, nacc[r]); dacc[r] = fmaf(q0.w, p, dacc[r]);
            }
            {
                float e = __builtin_amdgcn_exp2f(fmaf(-q1.x, x4.y, q1.y));
                float p = __builtin_amdgcn_rcpf(1.f + e);
                nacc[r] = fmaf(q1.z, p, nacc[r]); dacc[r] = fmaf(q1.w, p, dacc[r]);
            }
            {
                float e = __builtin_amdgcn_exp2f(fmaf(-q2.x, x4.z, q2.y));
                float p = __builtin_amdgcn_rcpf(1.f + e);
                nacc[r] = fmaf(q2.z, p, nacc[r]); dacc[r] = fmaf(q2.w, p, dacc[r]);
            }
            {
                float e = __builtin_amdgcn_exp2f(fmaf(-q3.x, x4.w, q3.y));
                float p = __builtin_amdgcn_rcpf(1.f + e);
                nacc[r] = fmaf(q3.z, p, nacc[r]); dacc[r] = fmaf(q3.w, p, dacc[r]);
            }
        }
    }
    #pragma unroll
    for (int r = 0; r < 4; ++r) {
        red[(((strip * 4 + r) * 64) + ul) * 2 + 0] = nacc[r];
        red[(((strip * 4 + r) * 64) + ul) * 2 + 1] = dacc[r];
    }
    __syncthreads();
    if (tid < 4 * 64) {
        const int r = tid >> 6, uu = tid & 63;
        float n = 0.f, d = 0.f;
        #pragma unroll
        for (int s = 0; s < 8; ++s) {
            n += red[(((s * 4 + r) * 64) + uu) * 2 + 0];
            d += red[(((s * 4 + r) * 64) + uu) * 2 + 1];
        }
        wnum_s[(b0 + r) * U_DIM + (u0 + uu)] = n;
        wden_s[(b0 + r) * U_DIM + (u0 + uu)] = d;
    }
}

// ---------- one ODE unfold: tile 4 rows x 64 u; 512 thr = 64 lanes x 8 strips (64 i each) ----------
__global__ __launch_bounds__(512, 8) void k_unfold(
    const float* __restrict__ vin, const float4* __restrict__ pf4,
    const float* __restrict__ wnum_s, const float* __restrict__ wden_s,
    const float* __restrict__ vleak, const float* __restrict__ gleak,
    const float* __restrict__ cm, float* __restrict__ vout) {
    __shared__ __align__(16) float vs[4 * U_DIM];    // 8 KB
    __shared__ float red[8 * 4 * 64 * 2];            // 16 KB
    const int tid = threadIdx.x;
    const int b0 = blockIdx.x * 4;
    const int u0 = blockIdx.y * 64;

    // stage 4 rows of v: 2048 floats = 512 float4, one per thread
    reinterpret_cast<float4*>(vs)[tid] =
        reinterpret_cast<const float4*>(vin + (size_t)b0 * U_DIM)[tid];
    __syncthreads();

    const int ul = tid & 63;
    const int strip = tid >> 6;
    const int u = u0 + ul;
    float nacc[4], dacc[4];
    #pragma unroll
    for (int r = 0; r < 4; ++r) { nacc[r] = 0.f; dacc[r] = 0.f; }

    const int i0 = strip * 64;
    for (int ic = 0; ic < 64; ic += 4) {
        const int i = i0 + ic;
        float4 q0 = pf4[(i + 0) * U_DIM + u];
        float4 q1 = pf4[(i + 1) * U_DIM + u];
        float4 q2 = pf4[(i + 2) * U_DIM + u];
        float4 q3 = pf4[(i + 3) * U_DIM + u];
        #pragma unroll
        for (int r = 0; r < 4; ++r) {
            const float4 v4 = *reinterpret_cast<const float4*>(&vs[r * U_DIM + i]);
            {
                float e = __builtin_amdgcn_exp2f(fmaf(-q0.x, v4.x, q0.y));
                float p = __builtin_amdgcn_rcpf(1.f + e);
                nacc[r] = fmaf(q0.z, p, nacc[r]); dacc[r] = fmaf(q0.w, p, dacc[r]);
            }
            {
                float e = __builtin_amdgcn_exp2f(fmaf(-q1.x, v4.y, q1.y));
                float p = __builtin_amdgcn_rcpf(1.f + e);
                nacc[r] = fmaf(q1.z, p, nacc[r]); dacc[r] = fmaf(q1.w, p, dacc[r]);
            }
            {
                float e = __builtin_amdgcn_exp2f(fmaf(-q2.x, v4.z, q2.y));
                float p = __builtin_amdgcn_rcpf(1.f + e);
                nacc[r] = fmaf(q2.z, p, nacc[r]); dacc[r] = fmaf(q2.w, p, dacc[r]);
            }
            {
                float e = __builtin_amdgcn_exp2f(fmaf(-q3.x, v4.w, q3.y));
                float p = __builtin_amdgcn_rcpf(1.f + e);
                nacc[r] = fmaf(q3.z, p, nacc[r]); dacc[r] = fmaf(q3.w, p, dacc[r]);
            }
        }
    }
    #pragma unroll
    for (int r = 0; r < 4; ++r) {
        red[(((strip * 4 + r) * 64) + ul) * 2 + 0] = nacc[r];
        red[(((strip * 4 + r) * 64) + ul) * 2 + 1] = dacc[r];
    }
    __syncthreads();
    if (tid < 4 * 64) {
        const int r = tid >> 6, uu = tid & 63;
        float n = 0.f, d = 0.f;
        #pragma unroll
        for (int s = 0; s < 8; ++s) {
            n += red[(((s * 4 + r) * 64) + uu) * 2 + 0];
            d += red[(((s * 4 + r) * 64) + uu) * 2 + 1];
        }
        const int gu = u0 + uu, gb = b0 + r;
        float vold = vs[r * U_DIM + gu];
        float gl = gleak[gu], c = cm[gu];
        float num = fmaf(c, vold, fmaf(gl, vleak[gu], n + wnum_s[gb * U_DIM + gu]));
        float den = c + gl + d + wden_s[gb * U_DIM + gu];
        vout[gb * U_DIM + gu] = num / den;
    }
}

// ---------- fallback (tiny ws): one block per batch row ----------
__global__ __launch_bounds__(512) void k_mono(
    const float* __restrict__ inputs, const float* __restrict__ state,
    const float* __restrict__ input_w, const float* __restrict__ input_b,
    const float* __restrict__ smu, const float* __restrict__ ssig,
    const float* __restrict__ sW, const float* __restrict__ serev,
    const float* __restrict__ mu, const float* __restrict__ sigma,
    const float* __restrict__ W, const float* __restrict__ erev,
    const float* __restrict__ vleak, const float* __restrict__ gleak,
    const float* __restrict__ cm, float* __restrict__ out) {
    __shared__ float xs[IN_DIM];
    __shared__ float vsh[U_DIM];
    const int b = blockIdx.x, u = threadIdx.x;
    if (u < IN_DIM) xs[u] = fmaf(inputs[b * IN_DIM + u], input_w[u], input_b[u]);
    vsh[u] = state[b * U_DIM + u];
    __syncthreads();
    float ns = 0.f, ds = 0.f;
    for (int i = 0; i < IN_DIM; ++i) {
        int pi = i * U_DIM + u;
        float e = __builtin_amdgcn_exp2f((smu[pi] - xs[i]) * (ssig[pi] * L2E));
        float p = __builtin_amdgcn_rcpf(1.f + e);
        float a = sW[pi] * p;
        ns = fmaf(a, serev[pi], ns);
        ds += a;
    }
    const float c = cm[u], gl = gleak[u], glvl = gl * vleak[u];
    for (int t = 0; t < 6; ++t) {
        float n = ns, d = ds;
        for (int i = 0; i < U_DIM; ++i) {
            int pi = i * U_DIM + u;
            float e = __builtin_amdgcn_exp2f((mu[pi] - vsh[i]) * (sigma[pi] * L2E));
            float p = __builtin_amdgcn_rcpf(1.f + e);
            float a = W[pi] * p;
            n = fmaf(a, erev[pi], n);
            d += a;
        }
        float vn = (fmaf(c, vsh[u], glvl) + n) / (c + gl + d);
        __syncthreads();
        vsh[u] = vn;
        __syncthreads();
    }
    out[b * U_DIM + u] = vsh[u];
}

extern "C" void kernel_launch(void* const* d_in, const int* in_sizes, int n_in,
                              void* d_out, int out_size, void* d_ws, size_t ws_size,
                              hipStream_t stream) {
    const float* inputs  = (const float*)d_in[0];
    const float* state   = (const float*)d_in[1];
    const float* input_w = (const float*)d_in[2];
    const float* input_b = (const float*)d_in[3];
    const float* smu     = (const float*)d_in[4];
    const float* ssig    = (const float*)d_in[5];
    const float* sW      = (const float*)d_in[6];
    const float* serev   = (const float*)d_in[7];
    const float* mu      = (const float*)d_in[8];
    const float* sigma   = (const float*)d_in[9];
    const float* W       = (const float*)d_in[10];
    const float* erev    = (const float*)d_in[11];
    const float* vleak   = (const float*)d_in[12];
    const float* gleak   = (const float*)d_in[13];
    const float* cm      = (const float*)d_in[14];
    float* out = (float*)d_out;

    const int B = in_sizes[1] / U_DIM;   // 512
    const size_t BU = (size_t)B * U_DIM;
    const size_t UU = (size_t)U_DIM * U_DIM;
    const size_t SU = (size_t)IN_DIM * U_DIM;
    const size_t need = (3 * BU + 4 * UU + 4 * SU) * sizeof(float);

    if (ws_size >= need) {
        float* f      = (float*)d_ws;
        float* wnum_s = f;
        float* wden_s = f + BU;
        float* vbuf   = f + 2 * BU;
        float4* pf4   = (float4*)(f + 3 * BU);
        float4* sf4   = (float4*)(f + 3 * BU + 4 * UU);

        const int nfuse = (int)(UU + SU);
        k_fuse<<<(nfuse + 255) / 256, 256, 0, stream>>>(mu, sigma, W, erev,
                                                        smu, ssig, sW, serev, pf4, sf4);
        dim3 grid(B / 4, U_DIM / 64);
        k_sensory<<<grid, 512, 0, stream>>>(inputs, input_w, input_b, sf4, wnum_s, wden_s);
        const float* vin = state;
        float* pong[2] = { vbuf, out };   // ends on out after 6 steps
        for (int t = 0; t < 6; ++t) {
            float* vo = pong[t & 1];
            k_unfold<<<grid, 512, 0, stream>>>(vin, pf4, wnum_s, wden_s,
                                               vleak, gleak, cm, vo);
            vin = vo;
        }
    } else {
        k_mono<<<B, U_DIM, 0, stream>>>(inputs, state, input_w, input_b,
                                        smu, ssig, sW, serev, mu, sigma, W, erev,
                                        vleak, gleak, cm, out);
    }
}

// Round 4
// 210.333 us; speedup vs baseline: 1.0607x; 1.0607x over previous
//
#include <hip/hip_runtime.h>

#define IN_DIM 256
#define U_DIM  512
#define L2E    1.44269504088896340736f

// ---------- prefuse params ----------
// recurrent: sm2 = (sigma*l2e, mu*sigma*l2e), wep = W*erev (W = |wep|, erev=+-1)
// sensory:   sf4 = (sigma*l2e, mu*sigma*l2e, W*erev, W)
__global__ void k_fuse(const float* __restrict__ mu, const float* __restrict__ sigma,
                       const float* __restrict__ W, const float* __restrict__ erev,
                       const float* __restrict__ smu, const float* __restrict__ ssig,
                       const float* __restrict__ sW, const float* __restrict__ serev,
                       float2* __restrict__ sm2, float* __restrict__ wep,
                       float4* __restrict__ sf4) {
    int i = blockIdx.x * blockDim.x + threadIdx.x;
    const int UU = U_DIM * U_DIM;
    const int SU = IN_DIM * U_DIM;
    if (i < UU) {
        float s = sigma[i] * L2E;
        sm2[i] = make_float2(s, mu[i] * s);
        wep[i] = W[i] * erev[i];
    } else if (i < UU + SU) {
        int j = i - UU;
        float s = ssig[j] * L2E;
        float w = sW[j];
        sf4[j] = make_float4(s, smu[j] * s, w * serev[j], w);
    }
}

// ---------- sensory sums: tile 4 rows x 64 u; 512 thr = 64 lanes x 8 strips (32 i each) ----------
__global__ __launch_bounds__(512, 8) void k_sensory(
    const float* __restrict__ inputs, const float* __restrict__ input_w,
    const float* __restrict__ input_b, const float4* __restrict__ sf4,
    float* __restrict__ wnum_s, float* __restrict__ wden_s) {
    __shared__ __align__(16) float xs[4 * IN_DIM];   // 4 KB
    __shared__ float red[8 * 4 * 64 * 2];            // 16 KB
    const int tid = threadIdx.x;
    const int b0 = blockIdx.x * 4;
    const int u0 = blockIdx.y * 64;

    #pragma unroll
    for (int k = 0; k < 2; ++k) {
        int idx = tid + k * 512;
        int r = idx >> 8, i = idx & 255;
        xs[idx] = fmaf(inputs[(b0 + r) * IN_DIM + i], input_w[i], input_b[i]);
    }
    __syncthreads();

    const int ul = tid & 63;
    const int strip = tid >> 6;
    const int u = u0 + ul;
    float nacc[4], dacc[4];
    #pragma unroll
    for (int r = 0; r < 4; ++r) { nacc[r] = 0.f; dacc[r] = 0.f; }

    const int i0 = strip * 32;
    for (int ic = 0; ic < 32; ic += 4) {
        const int i = i0 + ic;
        float4 q0 = sf4[(i + 0) * U_DIM + u];
        float4 q1 = sf4[(i + 1) * U_DIM + u];
        float4 q2 = sf4[(i + 2) * U_DIM + u];
        float4 q3 = sf4[(i + 3) * U_DIM + u];
        #pragma unroll
        for (int r = 0; r < 4; ++r) {
            const float4 x4 = *reinterpret_cast<const float4*>(&xs[r * IN_DIM + i]);
            {
                float e = __builtin_amdgcn_exp2f(fmaf(-q0.x, x4.x, q0.y));
                float p = __builtin_amdgcn_rcpf(1.f + e);
                nacc[r] = fmaf(q0.z, p, nacc[r]); dacc[r] = fmaf(q0.w, p, dacc[r]);
            }
            {
                float e = __builtin_amdgcn_exp2f(fmaf(-q1.x, x4.y, q1.y));
                float p = __builtin_amdgcn_rcpf(1.f + e);
                nacc[r] = fmaf(q1.z, p, nacc[r]); dacc[r] = fmaf(q1.w, p, dacc[r]);
            }
            {
                float e = __builtin_amdgcn_exp2f(fmaf(-q2.x, x4.z, q2.y));
                float p = __builtin_amdgcn_rcpf(1.f + e);
                nacc[r] = fmaf(q2.z, p, nacc[r]); dacc[r] = fmaf(q2.w, p, dacc[r]);
            }
            {
                float e = __builtin_amdgcn_exp2f(fmaf(-q3.x, x4.w, q3.y));
                float p = __builtin_amdgcn_rcpf(1.f + e);
                nacc[r] = fmaf(q3.z, p, nacc[r]); dacc[r] = fmaf(q3.w, p, dacc[r]);
            }
        }
    }
    #pragma unroll
    for (int r = 0; r < 4; ++r) {
        red[(((strip * 4 + r) * 64) + ul) * 2 + 0] = nacc[r];
        red[(((strip * 4 + r) * 64) + ul) * 2 + 1] = dacc[r];
    }
    __syncthreads();
    if (tid < 4 * 64) {
        const int r = tid >> 6, uu = tid & 63;
        float n = 0.f, d = 0.f;
        #pragma unroll
        for (int s = 0; s < 8; ++s) {
            n += red[(((s * 4 + r) * 64) + uu) * 2 + 0];
            d += red[(((s * 4 + r) * 64) + uu) * 2 + 1];
        }
        wnum_s[(b0 + r) * U_DIM + (u0 + uu)] = n;
        wden_s[(b0 + r) * U_DIM + (u0 + uu)] = d;
    }
}

// ---------- one ODE unfold ----------
// tile: 8 rows x 32 u; 512 thr = 8 waves; each wave = 2 half-strips of 32 lanes
// (lane&31 = u, lane>>5 = which i-strip). 16 strips x 32 i. Params 12B/(i,u),
// amortized over 8 rows -> 1.5 B/element of L2 traffic.
__global__ __launch_bounds__(512, 8) void k_unfold(
    const float* __restrict__ vin,
    const float2* __restrict__ sm2, const float* __restrict__ wep,
    const float* __restrict__ wnum_s, const float* __restrict__ wden_s,
    const float* __restrict__ vleak, const float* __restrict__ gleak,
    const float* __restrict__ cm, float* __restrict__ vout) {
    __shared__ __align__(16) float vs[8 * U_DIM];    // 16 KB
    __shared__ float red_n[8 * 8 * 32];              // 8 KB
    __shared__ float red_d[8 * 8 * 32];              // 8 KB
    const int tid = threadIdx.x;
    const int b0 = blockIdx.x * 8;
    const int u0 = blockIdx.y * 32;

    // stage 8 rows of v: 4096 floats = 1024 float4
    #pragma unroll
    for (int k = 0; k < 2; ++k) {
        int idx = tid + k * 512;
        reinterpret_cast<float4*>(vs)[idx] =
            reinterpret_cast<const float4*>(vin + (size_t)b0 * U_DIM)[idx];
    }
    __syncthreads();

    const int lane = tid & 63;
    const int w = tid >> 6;            // wave 0..7
    const int ulh = lane & 31;         // u within tile
    const int ih = lane >> 5;          // which half-strip
    const int strip = w * 2 + ih;      // 0..15
    const int u = u0 + ulh;
    const int i0 = strip * 32;

    float nacc[8], dacc[8];
    #pragma unroll
    for (int r = 0; r < 8; ++r) { nacc[r] = 0.f; dacc[r] = 0.f; }

    for (int ic = 0; ic < 32; ic += 4) {
        const int i = i0 + ic;
        float2 q0 = sm2[(i + 0) * U_DIM + u];
        float2 q1 = sm2[(i + 1) * U_DIM + u];
        float2 q2 = sm2[(i + 2) * U_DIM + u];
        float2 q3 = sm2[(i + 3) * U_DIM + u];
        float we0 = wep[(i + 0) * U_DIM + u];
        float we1 = wep[(i + 1) * U_DIM + u];
        float we2 = wep[(i + 2) * U_DIM + u];
        float we3 = wep[(i + 3) * U_DIM + u];
        float w0 = fabsf(we0), w1 = fabsf(we1), w2 = fabsf(we2), w3 = fabsf(we3);
        #pragma unroll
        for (int r = 0; r < 8; ++r) {
            // per-lane addr: two distinct 16B lines per wave (2-way, free)
            const float4 v4 = *reinterpret_cast<const float4*>(&vs[r * U_DIM + i]);
            {
                float e = __builtin_amdgcn_exp2f(fmaf(-q0.x, v4.x, q0.y));
                float p = __builtin_amdgcn_rcpf(1.f + e);
                nacc[r] = fmaf(we0, p, nacc[r]); dacc[r] = fmaf(w0, p, dacc[r]);
            }
            {
                float e = __builtin_amdgcn_exp2f(fmaf(-q1.x, v4.y, q1.y));
                float p = __builtin_amdgcn_rcpf(1.f + e);
                nacc[r] = fmaf(we1, p, nacc[r]); dacc[r] = fmaf(w1, p, dacc[r]);
            }
            {
                float e = __builtin_amdgcn_exp2f(fmaf(-q2.x, v4.z, q2.y));
                float p = __builtin_amdgcn_rcpf(1.f + e);
                nacc[r] = fmaf(we2, p, nacc[r]); dacc[r] = fmaf(w2, p, dacc[r]);
            }
            {
                float e = __builtin_amdgcn_exp2f(fmaf(-q3.x, v4.w, q3.y));
                float p = __builtin_amdgcn_rcpf(1.f + e);
                nacc[r] = fmaf(we3, p, nacc[r]); dacc[r] = fmaf(w3, p, dacc[r]);
            }
        }
    }

    // intra-wave reduce across the two half-strips (lane ^ 32)
    #pragma unroll
    for (int r = 0; r < 8; ++r) {
        nacc[r] += __shfl_xor(nacc[r], 32);
        dacc[r] += __shfl_xor(dacc[r], 32);
    }
    if (lane < 32) {
        #pragma unroll
        for (int r = 0; r < 8; ++r) {
            red_n[(w * 8 + r) * 32 + ulh] = nacc[r];
            red_d[(w * 8 + r) * 32 + ulh] = dacc[r];
        }
    }
    __syncthreads();
    if (tid < 8 * 32) {
        const int r = tid >> 5, uu = tid & 31;
        float n = 0.f, d = 0.f;
        #pragma unroll
        for (int s = 0; s < 8; ++s) {
            n += red_n[(s * 8 + r) * 32 + uu];
            d += red_d[(s * 8 + r) * 32 + uu];
        }
        const int gu = u0 + uu, gb = b0 + r;
        float vold = vs[r * U_DIM + gu];
        float gl = gleak[gu], c = cm[gu];
        float num = fmaf(c, vold, fmaf(gl, vleak[gu], n + wnum_s[gb * U_DIM + gu]));
        float den = c + gl + d + wden_s[gb * U_DIM + gu];
        vout[gb * U_DIM + gu] = num * __builtin_amdgcn_rcpf(den);
    }
}

// ---------- fallback (tiny ws): one block per batch row ----------
__global__ __launch_bounds__(512) void k_mono(
    const float* __restrict__ inputs, const float* __restrict__ state,
    const float* __restrict__ input_w, const float* __restrict__ input_b,
    const float* __restrict__ smu, const float* __restrict__ ssig,
    const float* __restrict__ sW, const float* __restrict__ serev,
    const float* __restrict__ mu, const float* __restrict__ sigma,
    const float* __restrict__ W, const float* __restrict__ erev,
    const float* __restrict__ vleak, const float* __restrict__ gleak,
    const float* __restrict__ cm, float* __restrict__ out) {
    __shared__ float xs[IN_DIM];
    __shared__ float vsh[U_DIM];
    const int b = blockIdx.x, u = threadIdx.x;
    if (u < IN_DIM) xs[u] = fmaf(inputs[b * IN_DIM + u], input_w[u], input_b[u]);
    vsh[u] = state[b * U_DIM + u];
    __syncthreads();
    float ns = 0.f, ds = 0.f;
    for (int i = 0; i < IN_DIM; ++i) {
        int pi = i * U_DIM + u;
        float e = __builtin_amdgcn_exp2f((smu[pi] - xs[i]) * (ssig[pi] * L2E));
        float p = __builtin_amdgcn_rcpf(1.f + e);
        float a = sW[pi] * p;
        ns = fmaf(a, serev[pi], ns);
        ds += a;
    }
    const float c = cm[u], gl = gleak[u], glvl = gl * vleak[u];
    for (int t = 0; t < 6; ++t) {
        float n = ns, d = ds;
        for (int i = 0; i < U_DIM; ++i) {
            int pi = i * U_DIM + u;
            float e = __builtin_amdgcn_exp2f((mu[pi] - vsh[i]) * (sigma[pi] * L2E));
            float p = __builtin_amdgcn_rcpf(1.f + e);
            float a = W[pi] * p;
            n = fmaf(a, erev[pi], n);
            d += a;
        }
        float vn = (fmaf(c, vsh[u], glvl) + n) / (c + gl + d);
        __syncthreads();
        vsh[u] = vn;
        __syncthreads();
    }
    out[b * U_DIM + u] = vsh[u];
}

extern "C" void kernel_launch(void* const* d_in, const int* in_sizes, int n_in,
                              void* d_out, int out_size, void* d_ws, size_t ws_size,
                              hipStream_t stream) {
    const float* inputs  = (const float*)d_in[0];
    const float* state   = (const float*)d_in[1];
    const float* input_w = (const float*)d_in[2];
    const float* input_b = (const float*)d_in[3];
    const float* smu     = (const float*)d_in[4];
    const float* ssig    = (const float*)d_in[5];
    const float* sW      = (const float*)d_in[6];
    const float* serev   = (const float*)d_in[7];
    const float* mu      = (const float*)d_in[8];
    const float* sigma   = (const float*)d_in[9];
    const float* W       = (const float*)d_in[10];
    const float* erev    = (const float*)d_in[11];
    const float* vleak   = (const float*)d_in[12];
    const float* gleak   = (const float*)d_in[13];
    const float* cm      = (const float*)d_in[14];
    float* out = (float*)d_out;

    const int B = in_sizes[1] / U_DIM;   // 512
    const size_t BU = (size_t)B * U_DIM;
    const size_t UU = (size_t)U_DIM * U_DIM;
    const size_t SU = (size_t)IN_DIM * U_DIM;
    const size_t need = (3 * BU + 3 * UU + 4 * SU) * sizeof(float);

    if (ws_size >= need) {
        float* f      = (float*)d_ws;
        float* wnum_s = f;
        float* wden_s = f + BU;
        float* vbuf   = f + 2 * BU;
        float2* sm2   = (float2*)(f + 3 * BU);
        float* wep    = f + 3 * BU + 2 * UU;
        float4* sf4   = (float4*)(f + 3 * BU + 3 * UU);

        const int nfuse = (int)(UU + SU);
        k_fuse<<<(nfuse + 255) / 256, 256, 0, stream>>>(mu, sigma, W, erev,
                                                        smu, ssig, sW, serev,
                                                        sm2, wep, sf4);
        dim3 sgrid(B / 4, U_DIM / 64);
        k_sensory<<<sgrid, 512, 0, stream>>>(inputs, input_w, input_b, sf4, wnum_s, wden_s);
        dim3 ugrid(B / 8, U_DIM / 32);   // 64 x 16 = 1024 blocks
        const float* vin = state;
        float* pong[2] = { vbuf, out };  // ends on out after 6 steps
        for (int t = 0; t < 6; ++t) {
            float* vo = pong[t & 1];
            k_unfold<<<ugrid, 512, 0, stream>>>(vin, sm2, wep, wnum_s, wden_s,
                                                vleak, gleak, cm, vo);
            vin = vo;
        }
    } else {
        k_mono<<<B, U_DIM, 0, stream>>>(inputs, state, input_w, input_b,
                                        smu, ssig, sW, serev, mu, sigma, W, erev,
                                        vleak, gleak, cm, out);
    }
}